// Round 8
// baseline (322.844 us; speedup 1.0000x reference)
//
#include <hip/hip_runtime.h>
#include <hip/hip_bf16.h>

// LSTM: B=8192, T=512, H=32. Block = 256 threads (4 waves) owning TWO
// 16-batch groups (32 batches); 256 blocks -> 1 block/CU, 4 waves/CU.
// The two groups' recurrences are interleaved inside each step so every
// latency gap (post-barrier b128 read, MFMA chain, exp2/rcp chain) of one
// group is filled by the other group's independent instructions (ILP, not
// TLP). One barrier per timestep covers both groups.
// Transposed MFMA D = W'*h (identity k-perm): tile t8 row m = (gate m&3,
// unit 8*(m>>2)+t8); C/D layout gives lane (c,q) reg r = gate r of cell
// (unit 8q+t8, batch c). Wave w owns tiles {2w, 2w+1} -> 2 cells/lane/group,
// adjacent unit-slots -> h exchange = one b32 (hi) + one b32 (lo) per group
// into ping-pong planes [qblk][batch][j]; next step's B-frag is a b128 read.
// Weights/biases shared across groups. hi/lo bf16 split (3 chained MFMAs) =
// fp32-grade matvec. Gates pre-scaled by -log2e (i,f,o) / +2log2e (g);
// cell = 5 exp2 + 2 rcp (exact identities).

#define TT 512
#define HH 32
#define L2E 1.44269504088896340736f

typedef short bf16x8 __attribute__((ext_vector_type(8)));
typedef float f32x4 __attribute__((ext_vector_type(4)));

__device__ __forceinline__ short f2bf(float f) {
    unsigned u = __float_as_uint(f);
    u = (u + 0x7FFFu + ((u >> 16) & 1u)) >> 16;
    return (short)u;
}
__device__ __forceinline__ float bf2f(short s) {
    return __uint_as_float(((unsigned)(unsigned short)s) << 16);
}
__device__ __forceinline__ float fastrcp(float x) { return __builtin_amdgcn_rcpf(x); }
__device__ __forceinline__ float exp2f_(float x) { return __builtin_amdgcn_exp2f(x); }

#define XROW 132            // x tile row stride (floats) -> 2-way banks max
#define XSZ  (16 * XROW)

__launch_bounds__(256, 1)
__global__ void lstm_kernel(const float* __restrict__ x,
                            const float* __restrict__ W_ih,
                            const float* __restrict__ W_hh,
                            const float* __restrict__ b_ih,
                            const float* __restrict__ b_hh,
                            const float* __restrict__ W_fc,
                            const float* __restrict__ b_fc,
                            float* __restrict__ out) {
    // h planes: [group][parity][qblk(4)][batch(16)][j(8)] shorts
    __shared__ short hhp[2][2][512];
    __shared__ short hlp[2][2][512];
    __shared__ float xbuf[2][XSZ];       // x tiles: [group][batch][t mod 128]

    const int tid  = threadIdx.x;
    const int lane = tid & 63;
    const int w    = tid >> 6;        // wave id 0..3: owns tiles 2w, 2w+1
    const int c    = lane & 15;       // batch (MFMA n); also A m-row
    const int q    = lane >> 4;       // quad: k-block 8q; unit-block 8q
    const int base = blockIdx.x * 32; // 32 batches = 2 groups per block

    // ---- A-fragments (weights) for tiles 2w+tt, hi/lo bf16 split (shared) --
    const int gate = c & 3;
    const float asc = (gate == 2) ? (2.0f * L2E) : (-L2E);
    const int wrow0 = gate * 32 + 8 * (c >> 2);
    bf16x8 wah[2], wal[2];
    #pragma unroll
    for (int tt = 0; tt < 2; ++tt) {
        const int t8 = 2 * w + tt;
        #pragma unroll
        for (int j = 0; j < 8; ++j) {
            const float wf = W_hh[(wrow0 + t8) * HH + 8 * q + j] * asc;
            const short hi = f2bf(wf);
            wah[tt][j] = hi;
            wal[tt][j] = f2bf(wf - bf2f(hi));
        }
    }

    // ---- per-cell consts (shared): cell tt = (unit 8q + 2w + tt) ----
    float wihs[2][4];
    f32x4 bcs[2];
    #pragma unroll
    for (int tt = 0; tt < 2; ++tt) {
        const int u = 8 * q + 2 * w + tt;
        #pragma unroll
        for (int r = 0; r < 4; ++r) {
            const float sc = (r == 2) ? (2.0f * L2E) : (-L2E);
            wihs[tt][r] = W_ih[32 * r + u] * sc;
            bcs[tt][r]  = (b_ih[32 * r + u] + b_hh[32 * r + u]) * sc;
        }
    }

    // ---- init parity-0 h planes (h0 = 0), both groups ----
    #pragma unroll
    for (int i = tid; i < 512; i += 256) {
        hhp[0][0][i] = 0; hlp[0][0][i] = 0;
        hhp[1][0][i] = 0; hlp[1][0][i] = 0;
    }

    float cs[2][2] = {{0.f, 0.f}, {0.f, 0.f}};   // [group][cell]

    const int rdo = q * 128 + c * 8;  // B-frag read offset (shorts)
    const int wro = rdo + 2 * w;      // h write offset (shorts)

    #define STEP(t, RP, WP)                                                   \
    {                                                                         \
        bf16x8 bhv[2], blv[2];                                                \
        float xc[2];                                                          \
        _Pragma("unroll")                                                     \
        for (int g = 0; g < 2; ++g) {                                         \
            bhv[g] = *(const bf16x8*)&hhp[g][RP][rdo];                        \
            blv[g] = *(const bf16x8*)&hlp[g][RP][rdo];                        \
            xc[g]  = xbuf[g][c * XROW + ((t) & 127)];                         \
        }                                                                     \
        f32x4 acc[2][2];                                                      \
        _Pragma("unroll")                                                     \
        for (int g = 0; g < 2; ++g) {                                         \
            _Pragma("unroll")                                                 \
            for (int tt = 0; tt < 2; ++tt) {                                  \
                f32x4 a = bcs[tt];                                            \
                a = __builtin_amdgcn_mfma_f32_16x16x32_bf16(wah[tt], bhv[g], a, 0,0,0); \
                a = __builtin_amdgcn_mfma_f32_16x16x32_bf16(wah[tt], blv[g], a, 0,0,0); \
                a = __builtin_amdgcn_mfma_f32_16x16x32_bf16(wal[tt], bhv[g], a, 0,0,0); \
                acc[g][tt] = a;                                               \
            }                                                                 \
        }                                                                     \
        _Pragma("unroll")                                                     \
        for (int g = 0; g < 2; ++g) {                                         \
            float hv[2];                                                      \
            _Pragma("unroll")                                                 \
            for (int tt = 0; tt < 2; ++tt) {                                  \
                const float Ei = exp2f_(acc[g][tt][0] + wihs[tt][0] * xc[g]); \
                const float Ef = exp2f_(acc[g][tt][1] + wihs[tt][1] * xc[g]); \
                const float G  = exp2f_(acc[g][tt][2] + wihs[tt][2] * xc[g]); \
                const float Eo = exp2f_(acc[g][tt][3] + wihs[tt][3] * xc[g]); \
                const float aig = (1.f + Ei) * (G + 1.f);                     \
                const float af  = 1.f + Ef;                                   \
                const float num = cs[g][tt] * aig + (G - 1.f) * af;           \
                const float cn  = num * fastrcp(af * aig);                    \
                cs[g][tt] = cn;                                               \
                float yc = cn * (2.0f * L2E);                                 \
                yc = fminf(60.f, fmaxf(-60.f, yc));                           \
                const float C = exp2f_(yc);                                   \
                hv[tt] = (C - 1.f) * fastrcp((C + 1.f) * (1.f + Eo));         \
            }                                                                 \
            union { __hip_bfloat162 b; int i; } ph, pl;                       \
            ph.b = __float22bfloat162_rn(make_float2(hv[0], hv[1]));          \
            const float h0h = bf2f((short)(ph.i & 0xFFFF));                   \
            const float h1h = bf2f((short)((unsigned)ph.i >> 16));            \
            pl.b = __float22bfloat162_rn(make_float2(hv[0] - h0h, hv[1] - h1h)); \
            *(int*)&hhp[g][WP][wro] = ph.i;                                   \
            *(int*)&hlp[g][WP][wro] = pl.i;                                   \
        }                                                                     \
        __syncthreads();                                                      \
    }

    for (int t = 0; t < TT; t += 2) {
        if ((t & 127) == 0) {
            // stage x tiles for both groups: 1024 float4 over 256 threads
            #pragma unroll
            for (int s = 0; s < 4; ++s) {
                const int lin = tid + 256 * s;
                const int g   = lin >> 9;
                const int row = (lin >> 5) & 15;
                const int j4  = (lin & 31) * 4;
                const float4 v =
                    *(const float4*)&x[(base + g * 16 + row) * TT + t + j4];
                *(float4*)&xbuf[g][row * XROW + j4] = v;
            }
            __syncthreads();
        }
        STEP(t,     0, 1);   // read parity 0 (h(t)), write parity 1 (h(t+1))
        STEP(t + 1, 1, 0);   // read parity 1, write parity 0
    }
    // T even -> final h in parity-0 planes; loop ended with a barrier.

    // ---- head: out[b] = h_T @ W_fc^T + b_fc ----
    if (tid < 32) {
        const int g  = tid >> 4;
        const int bb = tid & 15;
        float s = b_fc[0];
        #pragma unroll
        for (int u = 0; u < 32; ++u) {
            const int off = (u >> 3) * 128 + bb * 8 + (u & 7);
            s += (bf2f(hhp[g][0][off]) + bf2f(hlp[g][0][off])) * W_fc[u];
        }
        out[base + g * 16 + bb] = s;
    }
}

extern "C" void kernel_launch(void* const* d_in, const int* in_sizes, int n_in,
                              void* d_out, int out_size, void* d_ws, size_t ws_size,
                              hipStream_t stream) {
    const float* x    = (const float*)d_in[0];
    const float* W_ih = (const float*)d_in[1];
    const float* W_hh = (const float*)d_in[2];
    const float* b_ih = (const float*)d_in[3];
    const float* b_hh = (const float*)d_in[4];
    const float* W_fc = (const float*)d_in[5];
    const float* b_fc = (const float*)d_in[6];
    float* out = (float*)d_out;

    const int B = 8192;
    lstm_kernel<<<B / 32, 256, 0, stream>>>(x, W_ih, W_hh, b_ih, b_hh,
                                            W_fc, b_fc, out);
}

// Round 9
// 290.360 us; speedup vs baseline: 1.1119x; 1.1119x over previous
//
#include <hip/hip_runtime.h>
#include <hip/hip_bf16.h>

// LSTM: B=8192, T=512, H=32. Block = 256 threads (4 waves) per 16-batch group;
// 512 blocks -> 2 blocks/CU, 8 waves/CU (2/SIMD from different blocks).
// Transposed MFMA D = W'*h, tile t8 row m = (gate m&3, unit 8*(m>>2)+t8);
// C/D layout: lane (c,q) reg r = gate r of cell (unit 8q+t8, batch c).
// Wave w owns tiles {2w, 2w+1} -> 2 cells/lane, adjacent unit-slots.
// K-PERMUTATION pi_q(j) = j XOR 2q (q = k-block) applied to A-fragments,
// h-plane writes, and the head: h write bank becomes (c*4 + (w XOR q)) mod 32
// = 2-way = free (was 8-way in R7, 1.47e7 conflict cycles).
// h exchange: one b32 (hi) + one b32 (lo) per lane into ping-pong planes
// [qblk][batch][j]; next step's B-frag is a direct b128 read. 1 barrier/step.
// MFMA split into parallel chains a1 = Wh*hh ; a2 = Wh*hl + (Wl*hh + Cinit)
// with Cinit = bias + x-term -> one MFMA latency off the serial path.
// Gates pre-scaled by -log2e (i,f,o) / +2log2e (g); cell = 5 exp2 + 2 rcp.

#define TT 512
#define HH 32
#define L2E 1.44269504088896340736f

typedef short bf16x8 __attribute__((ext_vector_type(8)));
typedef float f32x4 __attribute__((ext_vector_type(4)));

__device__ __forceinline__ short f2bf(float f) {
    unsigned u = __float_as_uint(f);
    u = (u + 0x7FFFu + ((u >> 16) & 1u)) >> 16;
    return (short)u;
}
__device__ __forceinline__ float bf2f(short s) {
    return __uint_as_float(((unsigned)(unsigned short)s) << 16);
}
__device__ __forceinline__ float fastrcp(float x) { return __builtin_amdgcn_rcpf(x); }
__device__ __forceinline__ float exp2f_(float x) { return __builtin_amdgcn_exp2f(x); }

#define XROW 132   // x tile row stride (floats): bank (4c+t) mod 32 -> 2-way

__launch_bounds__(256, 2)
__global__ void lstm_kernel(const float* __restrict__ x,
                            const float* __restrict__ W_ih,
                            const float* __restrict__ W_hh,
                            const float* __restrict__ b_ih,
                            const float* __restrict__ b_hh,
                            const float* __restrict__ W_fc,
                            const float* __restrict__ b_fc,
                            float* __restrict__ out) {
    // h planes: [parity][qblk(4)][batch(16)][j(8)] shorts = 512 per parity
    __shared__ short hhp[2][512];
    __shared__ short hlp[2][512];
    __shared__ float xbuf[16 * XROW];

    const int tid  = threadIdx.x;
    const int lane = tid & 63;
    const int w    = tid >> 6;        // wave id 0..3: owns tiles 2w, 2w+1
    const int c    = lane & 15;       // batch (MFMA n); also A m-row
    const int q    = lane >> 4;       // quad: k-block 8q; unit-block 8q
    const int base = blockIdx.x * 16;

    // ---- A-fragments (weights) for tiles 2w+tt, hi/lo bf16 split ----
    // k-slot j of block q holds unit 8q + (j XOR 2q).
    const int gate = c & 3;
    const float asc = (gate == 2) ? (2.0f * L2E) : (-L2E);
    const int wrow0 = gate * 32 + 8 * (c >> 2);
    bf16x8 wah[2], wal[2];
    #pragma unroll
    for (int tt = 0; tt < 2; ++tt) {
        const int t8 = 2 * w + tt;
        #pragma unroll
        for (int j = 0; j < 8; ++j) {
            const int u = 8 * q + (j ^ (2 * q));
            const float wf = W_hh[(wrow0 + t8) * HH + u] * asc;
            const short hi = f2bf(wf);
            wah[tt][j] = hi;
            wal[tt][j] = f2bf(wf - bf2f(hi));
        }
    }

    // ---- per-cell consts: cell tt = (unit 8q + 2w + tt, batch c) ----
    float wihs[2][4];
    f32x4 bcs[2];
    #pragma unroll
    for (int tt = 0; tt < 2; ++tt) {
        const int u = 8 * q + 2 * w + tt;
        #pragma unroll
        for (int r = 0; r < 4; ++r) {
            const float sc = (r == 2) ? (2.0f * L2E) : (-L2E);
            wihs[tt][r] = W_ih[32 * r + u] * sc;
            bcs[tt][r]  = (b_ih[32 * r + u] + b_hh[32 * r + u]) * sc;
        }
    }

    // ---- init parity-0 h planes to zero (h0 = 0) ----
    #pragma unroll
    for (int i = tid; i < 512; i += 256) { hhp[0][i] = 0; hlp[0][i] = 0; }

    float cs[2] = {0.f, 0.f};

    // x staging: 16 rows x 128 floats, 512 float4 over 256 threads (2 each)
    const int xrow = tid >> 4;
    const int xj4  = (tid & 15) * 4;

    // B-frag read offset (shorts); h write offset with k-perm (pair-adjacent)
    const int rdo = q * 128 + c * 8;
    const int wro = rdo + ((2 * w) ^ (2 * q));

    #define STEP(t, RP, WP)                                                   \
    {                                                                         \
        const bf16x8 bh = *(const bf16x8*)&hhp[RP][rdo];                      \
        const bf16x8 bl = *(const bf16x8*)&hlp[RP][rdo];                      \
        const float xc = xbuf[c * XROW + ((t) & 127)];                        \
        f32x4 acc[2];                                                         \
        _Pragma("unroll")                                                     \
        for (int tt = 0; tt < 2; ++tt) {                                      \
            f32x4 ci;                                                         \
            _Pragma("unroll")                                                 \
            for (int r = 0; r < 4; ++r) ci[r] = wihs[tt][r] * xc + bcs[tt][r];\
            f32x4 a1 = {0.f, 0.f, 0.f, 0.f};                                  \
            a1 = __builtin_amdgcn_mfma_f32_16x16x32_bf16(wah[tt], bh, a1, 0,0,0);\
            f32x4 a2 = __builtin_amdgcn_mfma_f32_16x16x32_bf16(wal[tt], bh, ci, 0,0,0);\
            a2 = __builtin_amdgcn_mfma_f32_16x16x32_bf16(wah[tt], bl, a2, 0,0,0);\
            _Pragma("unroll")                                                 \
            for (int r = 0; r < 4; ++r) acc[tt][r] = a1[r] + a2[r];           \
        }                                                                     \
        float hv[2];                                                          \
        _Pragma("unroll")                                                     \
        for (int tt = 0; tt < 2; ++tt) {                                      \
            const float Ei = exp2f_(acc[tt][0]);                              \
            const float Ef = exp2f_(acc[tt][1]);                              \
            const float G  = exp2f_(acc[tt][2]);                              \
            const float Eo = exp2f_(acc[tt][3]);                              \
            const float aig = (1.f + Ei) * (G + 1.f);                         \
            const float af  = 1.f + Ef;                                       \
            const float num = cs[tt] * aig + (G - 1.f) * af;                  \
            const float cn  = num * fastrcp(af * aig);                        \
            cs[tt] = cn;                                                      \
            float yc = cn * (2.0f * L2E);                                     \
            yc = fminf(60.f, fmaxf(-60.f, yc));                               \
            const float C = exp2f_(yc);                                       \
            hv[tt] = (C - 1.f) * fastrcp((C + 1.f) * (1.f + Eo));             \
        }                                                                     \
        union { __hip_bfloat162 b; int i; } ph, pl;                           \
        ph.b = __float22bfloat162_rn(make_float2(hv[0], hv[1]));              \
        const float h0h = bf2f((short)(ph.i & 0xFFFF));                       \
        const float h1h = bf2f((short)((unsigned)ph.i >> 16));                \
        pl.b = __float22bfloat162_rn(make_float2(hv[0] - h0h, hv[1] - h1h));  \
        *(int*)&hhp[WP][wro] = ph.i;                                          \
        *(int*)&hlp[WP][wro] = pl.i;                                          \
        __syncthreads();                                                      \
    }

    for (int t = 0; t < TT; t += 2) {
        if ((t & 127) == 0) {
            #pragma unroll
            for (int s = 0; s < 2; ++s) {
                const float4 v = *(const float4*)&x[(base + xrow) * TT + t + xj4 + 64 * s];
                *(float4*)&xbuf[xrow * XROW + xj4 + 64 * s] = v;
            }
            __syncthreads();
        }
        STEP(t,     0, 1);   // read parity 0 (h(t)), write parity 1 (h(t+1))
        STEP(t + 1, 1, 0);   // read parity 1, write parity 0
    }
    // T even -> final h(512) is in parity-0 planes; loop ended with a barrier.

    // ---- head: out[b] = h_T @ W_fc^T + b_fc (k-perm aware) ----
    if (tid < 16) {
        float s = b_fc[0];
        #pragma unroll
        for (int u = 0; u < 32; ++u) {
            const int qb = u >> 3;
            const int off = qb * 128 + tid * 8 + ((u & 7) ^ (2 * qb));
            s += (bf2f(hhp[0][off]) + bf2f(hlp[0][off])) * W_fc[u];
        }
        out[base + tid] = s;
    }
}

extern "C" void kernel_launch(void* const* d_in, const int* in_sizes, int n_in,
                              void* d_out, int out_size, void* d_ws, size_t ws_size,
                              hipStream_t stream) {
    const float* x    = (const float*)d_in[0];
    const float* W_ih = (const float*)d_in[1];
    const float* W_hh = (const float*)d_in[2];
    const float* b_ih = (const float*)d_in[3];
    const float* b_hh = (const float*)d_in[4];
    const float* W_fc = (const float*)d_in[5];
    const float* b_fc = (const float*)d_in[6];
    float* out = (float*)d_out;

    const int B = 8192;
    lstm_kernel<<<B / 16, 256, 0, stream>>>(x, W_ih, W_hh, b_ih, b_hh,
                                            W_fc, b_fc, out);
}

// Round 11
// 248.499 us; speedup vs baseline: 1.2992x; 1.1685x over previous
//
#include <hip/hip_runtime.h>

// LSTM: B=8192, T=512, H=32. Block = 256 threads (4 waves) per 16-batch group;
// 512 blocks -> 2 blocks/CU, 8 waves/CU (2/SIMD from different blocks).
// Transposed MFMA D = W'*h via mfma_f32_16x16x32_f16: tile t8 row m =
// (gate m&3, unit 8*(m>>2)+t8); C/D layout: lane (c,q) reg r = gate r of cell
// (unit 8q+t8, batch c). Wave w owns tiles {2w, 2w+1} -> 2 cells/lane.
// FP16 2-TERM scheme: weights single fp16 (quantization ~2^-11 relative, gate
// error ~2e-4 abs), h split hi/lo fp16 (2 chained MFMAs: W*hh + W*hl).
// K-perm pi_q(j) = j XOR 2q keeps h-plane writes 2-way bank-aliased (free).
// h exchange: one b32 (hi) + one b32 (lo) per lane into ping-pong planes
// [qblk][batch][j]; next step's B-frag is a direct b128 read. 1 barrier/step.
// Cell math vectorized as float2 over the lane's two cells -> v_pk_*_f32.
// Gates pre-scaled by -log2e (i,f,o) / +2log2e (g); cell = 5 exp2 + 2 rcp.

#define TT 512
#define HH 32
#define L2E 1.44269504088896340736f

typedef _Float16 f16x8 __attribute__((ext_vector_type(8)));
typedef __fp16 fp16x2 __attribute__((ext_vector_type(2)));
typedef float f32x4 __attribute__((ext_vector_type(4)));
typedef float f32x2 __attribute__((ext_vector_type(2)));

__device__ __forceinline__ float fastrcp(float x) { return __builtin_amdgcn_rcpf(x); }
__device__ __forceinline__ float exp2f_(float x) { return __builtin_amdgcn_exp2f(x); }

#define XROW 132   // x tile row stride (floats): bank (4c+t) mod 32 -> 2-way

__launch_bounds__(256, 2)
__global__ void lstm_kernel(const float* __restrict__ x,
                            const float* __restrict__ W_ih,
                            const float* __restrict__ W_hh,
                            const float* __restrict__ b_ih,
                            const float* __restrict__ b_hh,
                            const float* __restrict__ W_fc,
                            const float* __restrict__ b_fc,
                            float* __restrict__ out) {
    // h planes: [parity][qblk(4)][batch(16)][j(8)] fp16 = 512 per parity
    __shared__ _Float16 hhp[2][512];   // h hi
    __shared__ _Float16 hlp[2][512];   // h lo
    __shared__ float xbuf[16 * XROW];

    const int tid  = threadIdx.x;
    const int lane = tid & 63;
    const int w    = tid >> 6;        // wave id 0..3: owns tiles 2w, 2w+1
    const int c    = lane & 15;       // batch (MFMA n); also A m-row
    const int q    = lane >> 4;       // quad: k-block 8q; unit-block 8q
    const int base = blockIdx.x * 16;

    // ---- A-fragments (weights) for tiles 2w+tt, single fp16 ----
    // k-slot j of block q holds unit 8q + (j XOR 2q).
    const int gate = c & 3;
    const float asc = (gate == 2) ? (2.0f * L2E) : (-L2E);
    const int wrow0 = gate * 32 + 8 * (c >> 2);
    f16x8 wah[2];
    #pragma unroll
    for (int tt = 0; tt < 2; ++tt) {
        const int t8 = 2 * w + tt;
        #pragma unroll
        for (int j = 0; j < 8; ++j) {
            const int u = 8 * q + (j ^ (2 * q));
            wah[tt][j] = (_Float16)(W_hh[(wrow0 + t8) * HH + u] * asc);
        }
    }

    // ---- per-cell consts: cell tt = (unit 8q + 2w + tt, batch c) ----
    f32x4 wihs[2], bcs[2];
    #pragma unroll
    for (int tt = 0; tt < 2; ++tt) {
        const int u = 8 * q + 2 * w + tt;
        #pragma unroll
        for (int r = 0; r < 4; ++r) {
            const float sc = (r == 2) ? (2.0f * L2E) : (-L2E);
            wihs[tt][r] = W_ih[32 * r + u] * sc;
            bcs[tt][r]  = (b_ih[32 * r + u] + b_hh[32 * r + u]) * sc;
        }
    }

    // ---- init parity-0 h planes to zero (h0 = 0) ----
    #pragma unroll
    for (int i = tid; i < 512; i += 256) {
        hhp[0][i] = (_Float16)0.f;
        hlp[0][i] = (_Float16)0.f;
    }

    f32x2 cs2 = {0.f, 0.f};          // c-state for cells tt=0,1

    // x staging: 16 rows x 128 floats, 512 float4 over 256 threads (2 each)
    const int xrow = tid >> 4;
    const int xj4  = (tid & 15) * 4;

    // B-frag read offset (fp16 units); h write offset with k-perm (even slot)
    const int rdo = q * 128 + c * 8;
    const int wro = rdo + ((2 * w) ^ (2 * q));

    #define STEP(t, RP, WP)                                                   \
    {                                                                         \
        const f16x8 bh = *(const f16x8*)&hhp[RP][rdo];                        \
        const f16x8 bl = *(const f16x8*)&hlp[RP][rdo];                        \
        const float xc = xbuf[c * XROW + ((t) & 127)];                        \
        f32x4 acc[2];                                                         \
        _Pragma("unroll")                                                     \
        for (int tt = 0; tt < 2; ++tt) {                                      \
            f32x4 a = wihs[tt] * xc + bcs[tt];                                \
            a = __builtin_amdgcn_mfma_f32_16x16x32_f16(wah[tt], bh, a, 0,0,0);\
            a = __builtin_amdgcn_mfma_f32_16x16x32_f16(wah[tt], bl, a, 0,0,0);\
            acc[tt] = a;                                                      \
        }                                                                     \
        f32x2 Ei, Ef, G, Eo;                                                  \
        Ei.x = exp2f_(acc[0][0]); Ei.y = exp2f_(acc[1][0]);                   \
        Ef.x = exp2f_(acc[0][1]); Ef.y = exp2f_(acc[1][1]);                   \
        G.x  = exp2f_(acc[0][2]); G.y  = exp2f_(acc[1][2]);                   \
        Eo.x = exp2f_(acc[0][3]); Eo.y = exp2f_(acc[1][3]);                   \
        const f32x2 one = {1.f, 1.f};                                         \
        const f32x2 aig = (one + Ei) * (G + one);                             \
        const f32x2 af  = one + Ef;                                           \
        const f32x2 num = cs2 * aig + (G - one) * af;                         \
        const f32x2 den = af * aig;                                           \
        f32x2 rc; rc.x = fastrcp(den.x); rc.y = fastrcp(den.y);               \
        const f32x2 cn = num * rc;                                            \
        cs2 = cn;                                                             \
        f32x2 yc = cn * (2.0f * L2E);                                         \
        yc.x = fminf(60.f, fmaxf(-60.f, yc.x));                               \
        yc.y = fminf(60.f, fmaxf(-60.f, yc.y));                               \
        f32x2 C; C.x = exp2f_(yc.x); C.y = exp2f_(yc.y);                      \
        const f32x2 hden = (C + one) * (one + Eo);                            \
        f32x2 hr; hr.x = fastrcp(hden.x); hr.y = fastrcp(hden.y);             \
        const f32x2 hv = (C - one) * hr;                                      \
        union { fp16x2 v; int i; _Float16 e[2]; } ph, pl;                     \
        ph.v = __builtin_amdgcn_cvt_pkrtz(hv.x, hv.y);                        \
        pl.v = __builtin_amdgcn_cvt_pkrtz(hv.x - (float)ph.e[0],              \
                                          hv.y - (float)ph.e[1]);             \
        *(int*)&hhp[WP][wro] = ph.i;                                          \
        *(int*)&hlp[WP][wro] = pl.i;                                          \
        __syncthreads();                                                      \
    }

    for (int t = 0; t < TT; t += 2) {
        if ((t & 127) == 0) {
            #pragma unroll
            for (int s = 0; s < 2; ++s) {
                const float4 v = *(const float4*)&x[(base + xrow) * TT + t + xj4 + 64 * s];
                *(float4*)&xbuf[xrow * XROW + xj4 + 64 * s] = v;
            }
            __syncthreads();
        }
        STEP(t,     0, 1);   // read parity 0 (h(t)), write parity 1 (h(t+1))
        STEP(t + 1, 1, 0);   // read parity 1, write parity 0
    }
    // T even -> final h(512) is in parity-0 planes; loop ended with a barrier.

    // ---- head: out[b] = h_T @ W_fc^T + b_fc (k-perm aware) ----
    if (tid < 16) {
        float s = b_fc[0];
        #pragma unroll
        for (int u = 0; u < 32; ++u) {
            const int qb = u >> 3;
            const int off = qb * 128 + tid * 8 + ((u & 7) ^ (2 * qb));
            s += ((float)hhp[0][off] + (float)hlp[0][off]) * W_fc[u];
        }
        out[base + tid] = s;
    }
}

extern "C" void kernel_launch(void* const* d_in, const int* in_sizes, int n_in,
                              void* d_out, int out_size, void* d_ws, size_t ws_size,
                              hipStream_t stream) {
    const float* x    = (const float*)d_in[0];
    const float* W_ih = (const float*)d_in[1];
    const float* W_hh = (const float*)d_in[2];
    const float* b_ih = (const float*)d_in[3];
    const float* b_hh = (const float*)d_in[4];
    const float* W_fc = (const float*)d_in[5];
    const float* b_fc = (const float*)d_in[6];
    float* out = (float*)d_out;

    const int B = 8192;
    lstm_kernel<<<B / 16, 256, 0, stream>>>(x, W_ih, W_hh, b_ih, b_hh,
                                            W_fc, b_fc, out);
}